// Round 3
// baseline (64.220 us; speedup 1.0000x reference)
//
#include <hip/hip_runtime.h>

#define EPS 1e-5f

typedef float f32x4 __attribute__((ext_vector_type(4)));

// One workgroup per (b, i): writes the contiguous 3-row stripe of the Hessian
// for atom i as lane-contiguous float4 nontemporal stores, then overwrites the
// diagonal 3x3 block after a block reduction.
__global__ __launch_bounds__(256) void c2s_kernel(
    const float* __restrict__ coords,
    const int*   __restrict__ num_atoms,
    float*       __restrict__ out,
    int N)
{
    const int i   = blockIdx.x;
    const int b   = blockIdx.y;
    const int tid = threadIdx.x;
    const int n3  = 3 * N;              // 3072

    const float* cb = coords + (size_t)b * n3;
    const int na   = num_atoms[b];
    const bool vi  = (i < na);

    const float cix = cb[3 * i + 0];
    const float ciy = cb[3 * i + 1];
    const float ciz = cb[3 * i + 2];

    // ---- pass 1: accumulate diagonal block (diag = +sum_j sep⊗sep/d2) ----
    float sxx = 0.f, sxy = 0.f, sxz = 0.f, syy = 0.f, syz = 0.f, szz = 0.f;
    for (int j = tid; j < N; j += 256) {
        const float m = (vi && (j < na)) ? 1.0f : 0.0f;
        const float dx = (cix - cb[3 * j + 0]) * m;
        const float dy = (ciy - cb[3 * j + 1]) * m;
        const float dz = (ciz - cb[3 * j + 2]) * m;
        const float inv = __builtin_amdgcn_rcpf(dx * dx + dy * dy + dz * dz + EPS);
        sxx += dx * dx * inv; sxy += dx * dy * inv; sxz += dx * dz * inv;
        syy += dy * dy * inv; syz += dy * dz * inv; szz += dz * dz * inv;
    }

    // ---- pass 2: stream the stripe as float4 nontemporal stores ----
    // stripe = rows 3i..3i+2 of the [3N x 3N] matrix: contiguous 3*n3 floats.
    float* stripe = out + ((size_t)b * n3 + (size_t)(3 * i)) * n3;
    const int fpr  = n3 >> 2;           // float4 per row (768)
    const int nf4  = 3 * fpr;           // float4 per stripe (2304)

    for (int f = tid; f < nf4; f += 256) {
        // row r (0..2) and float4-within-row without a runtime divide
        const int r  = (f >= fpr) + (f >= 2 * fpr);
        const int c  = (f - r * fpr) << 2;     // starting column 0..3068, %4==0
        const int j0 = c / 3;                  // const divisor -> magic mul
        const int c0 = c - 3 * j0;             // 0..2
        const int j1 = j0 + 1;                 // always <= N-1 when used

        // hess row r for partner j0
        const float mA = (vi && (j0 < na)) ? 1.0f : 0.0f;
        const float ax = (cix - cb[3 * j0 + 0]) * mA;
        const float ay = (ciy - cb[3 * j0 + 1]) * mA;
        const float az = (ciz - cb[3 * j0 + 2]) * mA;
        const float invA = __builtin_amdgcn_rcpf(ax * ax + ay * ay + az * az + EPS);
        const float drA  = (r == 0) ? ax : ((r == 1) ? ay : az);
        const float nA   = -drA * invA;
        const float vA0 = nA * ax, vA1 = nA * ay, vA2 = nA * az;

        // hess row r for partner j1
        const float mB = (vi && (j1 < na)) ? 1.0f : 0.0f;
        const float bx = (cix - cb[3 * j1 + 0]) * mB;
        const float by = (ciy - cb[3 * j1 + 1]) * mB;
        const float bz = (ciz - cb[3 * j1 + 2]) * mB;
        const float invB = __builtin_amdgcn_rcpf(bx * bx + by * by + bz * bz + EPS);
        const float drB  = (r == 0) ? bx : ((r == 1) ? by : bz);
        const float nB   = -drB * invB;
        const float vB0 = nB * bx, vB1 = nB * by, vB2 = nB * bz;

        f32x4 o;
        o.x = (c0 == 0) ? vA0 : ((c0 == 1) ? vA1 : vA2);
        o.y = (c0 == 0) ? vA1 : ((c0 == 1) ? vA2 : vB0);
        o.z = (c0 == 0) ? vA2 : ((c0 == 1) ? vB0 : vB1);
        o.w = (c0 == 0) ? vB0 : ((c0 == 1) ? vB1 : vB2);
        __builtin_nontemporal_store(o, reinterpret_cast<f32x4*>(stripe) + f);
    }

    // ---- reduction of the 6 diagonal sums ----
    #pragma unroll
    for (int off = 32; off > 0; off >>= 1) {
        sxx += __shfl_down(sxx, off);
        sxy += __shfl_down(sxy, off);
        sxz += __shfl_down(sxz, off);
        syy += __shfl_down(syy, off);
        syz += __shfl_down(syz, off);
        szz += __shfl_down(szz, off);
    }
    __shared__ float red[4][6];
    const int wave = tid >> 6;
    const int lane = tid & 63;
    if (lane == 0) {
        red[wave][0] = sxx; red[wave][1] = sxy; red[wave][2] = sxz;
        red[wave][3] = syy; red[wave][4] = syz; red[wave][5] = szz;
    }
    __syncthreads();   // drains vmcnt(0): all pass-2 stores are at L2 before diag write
    if (tid == 0) {
        const float dxx = red[0][0] + red[1][0] + red[2][0] + red[3][0];
        const float dxy = red[0][1] + red[1][1] + red[2][1] + red[3][1];
        const float dxz = red[0][2] + red[1][2] + red[2][2] + red[3][2];
        const float dyy = red[0][3] + red[1][3] + red[2][3] + red[3][3];
        const float dyz = red[0][4] + red[1][4] + red[2][4] + red[3][4];
        const float dzz = red[0][5] + red[1][5] + red[2][5] + red[3][5];
        float* r0 = stripe;
        float* r1 = r0 + n3;
        float* r2 = r1 + n3;
        r0[3 * i + 0] = dxx; r0[3 * i + 1] = dxy; r0[3 * i + 2] = dxz;
        r1[3 * i + 0] = dxy; r1[3 * i + 1] = dyy; r1[3 * i + 2] = dyz;
        r2[3 * i + 0] = dxz; r2[3 * i + 1] = dyz; r2[3 * i + 2] = dzz;
    }
}

extern "C" void kernel_launch(void* const* d_in, const int* in_sizes, int n_in,
                              void* d_out, int out_size, void* d_ws, size_t ws_size,
                              hipStream_t stream) {
    const float* coords    = (const float*)d_in[0];
    const int*   num_atoms = (const int*)d_in[1];
    float*       out       = (float*)d_out;

    const int B = in_sizes[1];             // 8
    const int N = in_sizes[0] / (3 * B);   // 1024

    dim3 grid(N, B);
    c2s_kernel<<<grid, 256, 0, stream>>>(coords, num_atoms, out, N);
}

// Round 4
// 55.779 us; speedup vs baseline: 1.1513x; 1.1513x over previous
//
#include <hip/hip_runtime.h>

#define EPS 1e-5f

typedef float f32x4 __attribute__((ext_vector_type(4)));

// One workgroup per (b, i): computes the 3-row stripe of the Hessian for atom
// i into LDS (compute identical to the 49.9us R1 kernel), patches the diagonal
// 3x3 block in LDS, then streams the stripe to global as lane-contiguous
// float4 stores (each wave-instruction = 1KB contiguous, fill-kernel pattern).
__global__ __launch_bounds__(256) void c2s_kernel(
    const float* __restrict__ coords,
    const int*   __restrict__ num_atoms,
    float*       __restrict__ out,
    int N)
{
    extern __shared__ float lds[];      // 3 * 3N floats = 36,864 B for N=1024

    const int i   = blockIdx.x;
    const int b   = blockIdx.y;
    const int tid = threadIdx.x;
    const int n3  = 3 * N;              // 3072

    const float* cb = coords + (size_t)b * n3;
    const int na   = num_atoms[b];
    const bool vi  = (i < na);

    const float cix = cb[3 * i + 0];
    const float ciy = cb[3 * i + 1];
    const float ciz = cb[3 * i + 2];

    float* l0 = lds;
    float* l1 = lds + n3;
    float* l2 = lds + 2 * n3;

    // ---- compute pass: hess blocks -> LDS, diag accumulates in regs ----
    float sxx = 0.f, sxy = 0.f, sxz = 0.f, syy = 0.f, syz = 0.f, szz = 0.f;
    for (int j = tid; j < N; j += 256) {
        const float m = (vi && (j < na)) ? 1.0f : 0.0f;
        const float dx = (cix - cb[3 * j + 0]) * m;
        const float dy = (ciy - cb[3 * j + 1]) * m;
        const float dz = (ciz - cb[3 * j + 2]) * m;
        const float inv = __builtin_amdgcn_rcpf(dx * dx + dy * dy + dz * dz + EPS);
        const float hxx = dx * dx * inv, hxy = dx * dy * inv, hxz = dx * dz * inv;
        const float hyy = dy * dy * inv, hyz = dy * dz * inv, hzz = dz * dz * inv;
        sxx += hxx; sxy += hxy; sxz += hxz;
        syy += hyy; syz += hyz; szz += hzz;
        l0[3 * j + 0] = -hxx; l0[3 * j + 1] = -hxy; l0[3 * j + 2] = -hxz;
        l1[3 * j + 0] = -hxy; l1[3 * j + 1] = -hyy; l1[3 * j + 2] = -hyz;
        l2[3 * j + 0] = -hxz; l2[3 * j + 1] = -hyz; l2[3 * j + 2] = -hzz;
    }

    // ---- reduce the 6 diagonal sums across the block ----
    #pragma unroll
    for (int off = 32; off > 0; off >>= 1) {
        sxx += __shfl_down(sxx, off);
        sxy += __shfl_down(sxy, off);
        sxz += __shfl_down(sxz, off);
        syy += __shfl_down(syy, off);
        syz += __shfl_down(syz, off);
        szz += __shfl_down(szz, off);
    }
    __shared__ float red[4][6];
    const int wave = tid >> 6;
    const int lane = tid & 63;
    if (lane == 0) {
        red[wave][0] = sxx; red[wave][1] = sxy; red[wave][2] = sxz;
        red[wave][3] = syy; red[wave][4] = syz; red[wave][5] = szz;
    }
    __syncthreads();
    if (tid == 0) {
        // diag block = +sum_j sep⊗sep/d2 ; patch into LDS at cols 3i..3i+2
        const float dxx = red[0][0] + red[1][0] + red[2][0] + red[3][0];
        const float dxy = red[0][1] + red[1][1] + red[2][1] + red[3][1];
        const float dxz = red[0][2] + red[1][2] + red[2][2] + red[3][2];
        const float dyy = red[0][3] + red[1][3] + red[2][3] + red[3][3];
        const float dyz = red[0][4] + red[1][4] + red[2][4] + red[3][4];
        const float dzz = red[0][5] + red[1][5] + red[2][5] + red[3][5];
        l0[3 * i + 0] = dxx; l0[3 * i + 1] = dxy; l0[3 * i + 2] = dxz;
        l1[3 * i + 0] = dxy; l1[3 * i + 1] = dyy; l1[3 * i + 2] = dyz;
        l2[3 * i + 0] = dxz; l2[3 * i + 1] = dyz; l2[3 * i + 2] = dzz;
    }
    __syncthreads();

    // ---- stream pass: LDS -> global, lane-contiguous float4 ----
    f32x4*       dst = reinterpret_cast<f32x4*>(out + ((size_t)b * n3 + (size_t)(3 * i)) * n3);
    const f32x4* src = reinterpret_cast<const f32x4*>(lds);
    const int nf4 = (3 * n3) >> 2;      // 2304
    for (int f = tid; f < nf4; f += 256)
        dst[f] = src[f];
}

extern "C" void kernel_launch(void* const* d_in, const int* in_sizes, int n_in,
                              void* d_out, int out_size, void* d_ws, size_t ws_size,
                              hipStream_t stream) {
    const float* coords    = (const float*)d_in[0];
    const int*   num_atoms = (const int*)d_in[1];
    float*       out       = (float*)d_out;

    const int B = in_sizes[1];             // 8
    const int N = in_sizes[0] / (3 * B);   // 1024

    dim3 grid(N, B);
    size_t shmem = (size_t)(3 * 3 * N) * sizeof(float);   // 36,864 B
    c2s_kernel<<<grid, 256, shmem, stream>>>(coords, num_atoms, out, N);
}

// Round 5
// 50.630 us; speedup vs baseline: 1.2684x; 1.1017x over previous
//
#include <hip/hip_runtime.h>

#define EPS 1e-5f

// One workgroup per (b, i): computes the full 3-row stripe of the Hessian
// for atom i, accumulating the diagonal 3x3 block on the fly.
// NT = compile-time N (0 = generic/runtime N).
template<int NT>
__global__ __launch_bounds__(256) void c2s_kernel(
    const float* __restrict__ coords,
    const int*   __restrict__ num_atoms,
    float*       __restrict__ out,
    int Nrt)
{
    const int N   = NT ? NT : Nrt;
    const int i   = blockIdx.x;
    const int b   = blockIdx.y;
    const int tid = threadIdx.x;
    const int n3  = 3 * N;

    const float* cb = coords + (size_t)b * n3;
    const int na   = num_atoms[b];
    const bool vi  = (i < na);

    const float cix = cb[3 * i + 0];
    const float ciy = cb[3 * i + 1];
    const float ciz = cb[3 * i + 2];

    float sxx = 0.f, sxy = 0.f, sxz = 0.f, syy = 0.f, syz = 0.f, szz = 0.f;

    float* r0 = out + ((size_t)b * n3 + (size_t)(3 * i)) * n3;
    float* r1 = r0 + n3;
    float* r2 = r1 + n3;

    #pragma unroll
    for (int j0 = 0; j0 < (NT ? NT : 1) * (NT ? 1 : 1); j0 += 256) {
        if (!NT && j0 >= N) break;           // generic path guard
        const int j = j0 + tid;
        const float m = (vi && (j < na)) ? 1.0f : 0.0f;
        const float dx = (cix - cb[3 * j + 0]) * m;
        const float dy = (ciy - cb[3 * j + 1]) * m;
        const float dz = (ciz - cb[3 * j + 2]) * m;
        const float inv = __builtin_amdgcn_rcpf(dx * dx + dy * dy + dz * dz + EPS);
        const float hxx = dx * dx * inv, hxy = dx * dy * inv, hxz = dx * dz * inv;
        const float hyy = dy * dy * inv, hyz = dy * dz * inv, hzz = dz * dz * inv;
        sxx += hxx; sxy += hxy; sxz += hxz;
        syy += hyy; syz += hyz; szz += hzz;
        if (j != i) {
            r0[3 * j + 0] = -hxx; r0[3 * j + 1] = -hxy; r0[3 * j + 2] = -hxz;
            r1[3 * j + 0] = -hxy; r1[3 * j + 1] = -hyy; r1[3 * j + 2] = -hyz;
            r2[3 * j + 0] = -hxz; r2[3 * j + 1] = -hyz; r2[3 * j + 2] = -hzz;
        }
        if (NT && j0 + 256 >= NT) break;     // loop bound for unrolled path
    }

    // block-wide reduction of the 6 unique diagonal-block sums
    #pragma unroll
    for (int off = 32; off > 0; off >>= 1) {
        sxx += __shfl_down(sxx, off);
        sxy += __shfl_down(sxy, off);
        sxz += __shfl_down(sxz, off);
        syy += __shfl_down(syy, off);
        syz += __shfl_down(syz, off);
        szz += __shfl_down(szz, off);
    }
    __shared__ float red[4][6];
    const int wave = tid >> 6;
    const int lane = tid & 63;
    if (lane == 0) {
        red[wave][0] = sxx; red[wave][1] = sxy; red[wave][2] = sxz;
        red[wave][3] = syy; red[wave][4] = syz; red[wave][5] = szz;
    }
    __syncthreads();
    if (tid == 0) {
        const float dxx = red[0][0] + red[1][0] + red[2][0] + red[3][0];
        const float dxy = red[0][1] + red[1][1] + red[2][1] + red[3][1];
        const float dxz = red[0][2] + red[1][2] + red[2][2] + red[3][2];
        const float dyy = red[0][3] + red[1][3] + red[2][3] + red[3][3];
        const float dyz = red[0][4] + red[1][4] + red[2][4] + red[3][4];
        const float dzz = red[0][5] + red[1][5] + red[2][5] + red[3][5];
        r0[3 * i + 0] = dxx; r0[3 * i + 1] = dxy; r0[3 * i + 2] = dxz;
        r1[3 * i + 0] = dxy; r1[3 * i + 1] = dyy; r1[3 * i + 2] = dyz;
        r2[3 * i + 0] = dxz; r2[3 * i + 1] = dyz; r2[3 * i + 2] = dzz;
    }
}

extern "C" void kernel_launch(void* const* d_in, const int* in_sizes, int n_in,
                              void* d_out, int out_size, void* d_ws, size_t ws_size,
                              hipStream_t stream) {
    const float* coords    = (const float*)d_in[0];
    const int*   num_atoms = (const int*)d_in[1];
    float*       out       = (float*)d_out;

    const int B = in_sizes[1];             // 8
    const int N = in_sizes[0] / (3 * B);   // 1024

    dim3 grid(N, B);
    if (N == 1024)
        c2s_kernel<1024><<<grid, 256, 0, stream>>>(coords, num_atoms, out, N);
    else
        c2s_kernel<0><<<grid, 256, 0, stream>>>(coords, num_atoms, out, N);
}